// Round 1
// baseline (3272.120 us; speedup 1.0000x reference)
//
#include <hip/hip_runtime.h>

#define N_NODES 50000
#define N_EDGES 800000
// F_KEY_NFEAT = 64, scale = 1/sqrt(64) = 0.125
// fiber2head: head h of a 64-float row = [f0[2h], f0[2h+1], f1[6h..6h+5]]
//   where f0 is the (16,1) part (16 floats) and f1 the (16,3) part (48 floats).

__global__ __launch_bounds__(256) void k_logits(
    const float* __restrict__ k0, const float* __restrict__ k1,
    const float* __restrict__ q0, const float* __restrict__ q1,
    const int* __restrict__ ei, float* __restrict__ e_out,
    float* __restrict__ s)
{
    int e = blockIdx.x * blockDim.x + threadIdx.x;
    if (e >= N_EDGES) return;
    int row = ei[e];
    int col = ei[N_EDGES + e];

    const float4* k0v = (const float4*)(k0 + (size_t)e   * 16);
    const float4* q0v = (const float4*)(q0 + (size_t)col * 16);
    const float4* k1v = (const float4*)(k1 + (size_t)e   * 48);
    const float4* q1v = (const float4*)(q1 + (size_t)col * 48);

    float acc[8];
    #pragma unroll
    for (int h = 0; h < 8; ++h) acc[h] = 0.f;

    // k0 part: flat idx m -> head m/2
    #pragma unroll
    for (int i = 0; i < 4; ++i) {
        float4 kv = k0v[i];
        float4 qv = q0v[i];
        acc[(4*i+0)/2] += kv.x * qv.x;
        acc[(4*i+1)/2] += kv.y * qv.y;
        acc[(4*i+2)/2] += kv.z * qv.z;
        acc[(4*i+3)/2] += kv.w * qv.w;
    }
    // k1 part: flat idx f -> head f/6
    #pragma unroll
    for (int j = 0; j < 12; ++j) {
        float4 kv = k1v[j];
        float4 qv = q1v[j];
        acc[(4*j+0)/6] += kv.x * qv.x;
        acc[(4*j+1)/6] += kv.y * qv.y;
        acc[(4*j+2)/6] += kv.z * qv.z;
        acc[(4*j+3)/6] += kv.w * qv.w;
    }

    float ex[8];
    #pragma unroll
    for (int h = 0; h < 8; ++h) ex[h] = __expf(acc[h] * 0.125f);

    float4* ev = (float4*)(e_out + (size_t)e * 8);
    ev[0] = make_float4(ex[0], ex[1], ex[2], ex[3]);
    ev[1] = make_float4(ex[4], ex[5], ex[6], ex[7]);

    float* sp = s + (size_t)row * 8;
    #pragma unroll
    for (int h = 0; h < 8; ++h) atomicAdd(sp + h, ex[h]);
}

__global__ __launch_bounds__(256) void k_scatter(
    const float* __restrict__ v0, const float* __restrict__ v1,
    const int* __restrict__ ei, const float* __restrict__ e_in,
    const float* __restrict__ s, float* __restrict__ out0,
    float* __restrict__ out1)
{
    int e = blockIdx.x * blockDim.x + threadIdx.x;
    if (e >= N_EDGES) return;
    int row = ei[e];
    int col = ei[N_EDGES + e];

    const float4* ev = (const float4*)(e_in + (size_t)e   * 8);
    const float4* sv = (const float4*)(s    + (size_t)row * 8);
    float4 ea = ev[0], eb = ev[1];
    float4 sa = sv[0], sb = sv[1];
    float a[8];
    a[0] = ea.x / sa.x; a[1] = ea.y / sa.y; a[2] = ea.z / sa.z; a[3] = ea.w / sa.w;
    a[4] = eb.x / sb.x; a[5] = eb.y / sb.y; a[6] = eb.z / sb.z; a[7] = eb.w / sb.w;

    // out0[col, m] += a[m/2] * v0[e, m],  m in [0,16)
    const float4* v0v = (const float4*)(v0 + (size_t)e * 16);
    float* o0 = out0 + (size_t)col * 16;
    #pragma unroll
    for (int i = 0; i < 4; ++i) {
        float4 vv = v0v[i];
        atomicAdd(o0 + 4*i + 0, a[(4*i+0)/2] * vv.x);
        atomicAdd(o0 + 4*i + 1, a[(4*i+1)/2] * vv.y);
        atomicAdd(o0 + 4*i + 2, a[(4*i+2)/2] * vv.z);
        atomicAdd(o0 + 4*i + 3, a[(4*i+3)/2] * vv.w);
    }
    // out1[col, f] += a[f/6] * v1[e, f],  f in [0,48)
    const float4* v1v = (const float4*)(v1 + (size_t)e * 48);
    float* o1 = out1 + (size_t)col * 48;
    #pragma unroll
    for (int j = 0; j < 12; ++j) {
        float4 vv = v1v[j];
        atomicAdd(o1 + 4*j + 0, a[(4*j+0)/6] * vv.x);
        atomicAdd(o1 + 4*j + 1, a[(4*j+1)/6] * vv.y);
        atomicAdd(o1 + 4*j + 2, a[(4*j+2)/6] * vv.z);
        atomicAdd(o1 + 4*j + 3, a[(4*j+3)/6] * vv.w);
    }
}

extern "C" void kernel_launch(void* const* d_in, const int* in_sizes, int n_in,
                              void* d_out, int out_size, void* d_ws, size_t ws_size,
                              hipStream_t stream) {
    const float* v0 = (const float*)d_in[0];
    const float* v1 = (const float*)d_in[1];
    const float* k0 = (const float*)d_in[2];
    const float* k1 = (const float*)d_in[3];
    const float* q0 = (const float*)d_in[4];
    const float* q1 = (const float*)d_in[5];
    const int*   ei = (const int*)d_in[6];

    float* out0 = (float*)d_out;                       // N*16 floats
    float* out1 = out0 + (size_t)N_NODES * 16;         // N*48 floats

    float* s     = (float*)d_ws;                       // N*8 floats
    float* e_buf = s + (size_t)N_NODES * 8;            // E*8 floats

    // Harness poisons d_out / d_ws with 0xAA before every call — zero what we accumulate into.
    hipMemsetAsync(d_out, 0, (size_t)out_size * sizeof(float), stream);
    hipMemsetAsync(s, 0, (size_t)N_NODES * 8 * sizeof(float), stream);

    const int block = 256;
    const int grid  = (N_EDGES + block - 1) / block;
    k_logits <<<grid, block, 0, stream>>>(k0, k1, q0, q1, ei, e_buf, s);
    k_scatter<<<grid, block, 0, stream>>>(v0, v1, ei, e_buf, s, out0, out1);
}

// Round 2
// 824.386 us; speedup vs baseline: 3.9692x; 3.9692x over previous
//
#include <hip/hip_runtime.h>
#include <hip/hip_fp16.h>

#define N_NODES 50000
#define N_EDGES 800000
// F_KEY_NFEAT = 64, scale = 1/sqrt(64) = 0.125
// fiber2head: head h of a 64-float row = [f0[2h], f0[2h+1], f1[6h..6h+5]]

struct alignas(16) H8 { __half h[8]; };

// ---------------- 1. degree histogram (int atomics only) ----------------
__global__ __launch_bounds__(256) void k_hist(const int* __restrict__ ei,
                                              int* __restrict__ cnt_r,
                                              int* __restrict__ cnt_c)
{
    int e = blockIdx.x * blockDim.x + threadIdx.x;
    if (e >= N_EDGES) return;
    atomicAdd(cnt_r + ei[e], 1);
    atomicAdd(cnt_c + ei[N_EDGES + e], 1);
}

// ---------------- 2. exclusive scan of both degree arrays ----------------
#define SCAN_T 1024
#define SCAN_I 8
__global__ __launch_bounds__(SCAN_T) void k_scan2(int* cnt_r, int* off_r,
                                                  int* cnt_c, int* off_c)
{
    __shared__ int sm[SCAN_T];
    __shared__ int carry_s;
    const int n = N_NODES;
    for (int pass = 0; pass < 2; ++pass) {
        int* cnt = pass ? cnt_c : cnt_r;
        int* off = pass ? off_c : off_r;
        if (threadIdx.x == 0) carry_s = 0;
        __syncthreads();
        for (int base = 0; base < n; base += SCAN_T * SCAN_I) {
            int idx0 = base + threadIdx.x * SCAN_I;
            int v[SCAN_I];
            int sum = 0;
            #pragma unroll
            for (int j = 0; j < SCAN_I; ++j) {
                int i = idx0 + j;
                v[j] = (i < n) ? cnt[i] : 0;
                sum += v[j];
            }
            sm[threadIdx.x] = sum;
            __syncthreads();
            for (int d = 1; d < SCAN_T; d <<= 1) {
                int t = (threadIdx.x >= d) ? sm[threadIdx.x - d] : 0;
                __syncthreads();
                sm[threadIdx.x] += t;
                __syncthreads();
            }
            int excl_thread = sm[threadIdx.x] - sum;
            int carry = carry_s;
            int run = carry + excl_thread;
            #pragma unroll
            for (int j = 0; j < SCAN_I; ++j) {
                int i = idx0 + j;
                if (i < n) { off[i] = run; cnt[i] = run; }  // cnt becomes fill cursor
                run += v[j];
            }
            __syncthreads();
            if (threadIdx.x == SCAN_T - 1) carry_s = carry + sm[threadIdx.x];
            __syncthreads();
        }
        if (threadIdx.x == 0) off[n] = carry_s;
        __syncthreads();
    }
}

// ---------------- 3. logits + exp (f16) + CSR fill ----------------
__global__ __launch_bounds__(256) void k_logits_fill(
    const float* __restrict__ k0, const float* __restrict__ k1,
    const float* __restrict__ q0, const float* __restrict__ q1,
    const int* __restrict__ ei, __half* __restrict__ e_buf,
    int* __restrict__ cur_r, int* __restrict__ cur_c,
    int* __restrict__ eid_r, int* __restrict__ eid_c)
{
    int e = blockIdx.x * blockDim.x + threadIdx.x;
    if (e >= N_EDGES) return;
    int row = ei[e];
    int col = ei[N_EDGES + e];

    const float4* k0v = (const float4*)(k0 + (size_t)e   * 16);
    const float4* q0v = (const float4*)(q0 + (size_t)col * 16);
    const float4* k1v = (const float4*)(k1 + (size_t)e   * 48);
    const float4* q1v = (const float4*)(q1 + (size_t)col * 48);

    float acc[8];
    #pragma unroll
    for (int h = 0; h < 8; ++h) acc[h] = 0.f;

    #pragma unroll
    for (int i = 0; i < 4; ++i) {
        float4 kv = k0v[i];
        float4 qv = q0v[i];
        acc[(4*i+0)/2] += kv.x * qv.x;
        acc[(4*i+1)/2] += kv.y * qv.y;
        acc[(4*i+2)/2] += kv.z * qv.z;
        acc[(4*i+3)/2] += kv.w * qv.w;
    }
    #pragma unroll
    for (int j = 0; j < 12; ++j) {
        float4 kv = k1v[j];
        float4 qv = q1v[j];
        acc[(4*j+0)/6] += kv.x * qv.x;
        acc[(4*j+1)/6] += kv.y * qv.y;
        acc[(4*j+2)/6] += kv.z * qv.z;
        acc[(4*j+3)/6] += kv.w * qv.w;
    }

    H8 pack;
    #pragma unroll
    for (int h = 0; h < 8; ++h) pack.h[h] = __float2half(__expf(acc[h] * 0.125f));
    *(H8*)(e_buf + (size_t)e * 8) = pack;

    int pr = atomicAdd(cur_r + row, 1);
    eid_r[pr] = e;
    int pc = atomicAdd(cur_c + col, 1);
    eid_c[pc] = e;
}

// ---------------- 4. softmax denominator via row-CSR gather ----------------
__global__ __launch_bounds__(256) void k_s(const __half* __restrict__ e_buf,
                                           const int* __restrict__ off_r,
                                           const int* __restrict__ eid_r,
                                           float* __restrict__ s)
{
    int t = blockIdx.x * blockDim.x + threadIdx.x;
    int node = t >> 3;
    int h = t & 7;
    if (node >= N_NODES) return;
    int beg = off_r[node], end = off_r[node + 1];
    float acc = 0.f;
    for (int i = beg; i < end; ++i) {
        int eid = eid_r[i];
        acc += __half2float(e_buf[(size_t)eid * 8 + h]);
    }
    s[(size_t)node * 8 + h] = acc;
}

// ---------------- 5. output via col-CSR gather: 1 wave/node, lane=feature ----------------
__global__ __launch_bounds__(256) void k_out(
    const float* __restrict__ v0, const float* __restrict__ v1,
    const int* __restrict__ ei, const __half* __restrict__ e_buf,
    const float* __restrict__ s,
    const int* __restrict__ off_c, const int* __restrict__ eid_c,
    float* __restrict__ out0, float* __restrict__ out1)
{
    int wave = (blockIdx.x * blockDim.x + threadIdx.x) >> 6;
    int lane = threadIdx.x & 63;
    if (wave >= N_NODES) return;
    int node = wave;
    bool is0 = lane < 16;
    int f1 = lane - 16;                       // index into the 48-float v1 row
    int head = is0 ? (lane >> 1) : (f1 / 6);

    int beg = off_c[node], end = off_c[node + 1];
    float acc = 0.f;
    for (int i = beg; i < end; ++i) {
        int eid = eid_c[i];                   // broadcast (same addr all lanes)
        int row = ei[eid];                    // broadcast
        float ev = __half2float(e_buf[(size_t)eid * 8 + head]);
        float sv = s[(size_t)row * 8 + head];
        float a = ev / sv;
        float v = is0 ? v0[(size_t)eid * 16 + lane]
                      : v1[(size_t)eid * 48 + f1];
        acc += a * v;
    }
    if (is0) out0[(size_t)node * 16 + lane] = acc;
    else     out1[(size_t)node * 48 + f1]   = acc;
}

extern "C" void kernel_launch(void* const* d_in, const int* in_sizes, int n_in,
                              void* d_out, int out_size, void* d_ws, size_t ws_size,
                              hipStream_t stream) {
    const float* v0 = (const float*)d_in[0];
    const float* v1 = (const float*)d_in[1];
    const float* k0 = (const float*)d_in[2];
    const float* k1 = (const float*)d_in[3];
    const float* q0 = (const float*)d_in[4];
    const float* q1 = (const float*)d_in[5];
    const int*   ei = (const int*)d_in[6];

    float* out0 = (float*)d_out;                      // N*16 floats
    float* out1 = out0 + (size_t)N_NODES * 16;        // N*48 floats

    // ---- workspace layout (bytes, all 16B-aligned), total ~21.6 MB ----
    char* ws = (char*)d_ws;
    float*  s     = (float*) (ws + 0);                        // N*8*4    = 1,600,000
    __half* e_buf = (__half*)(ws + 1600000);                  // E*8*2    = 12,800,000
    int*    cnt_r = (int*)   (ws + 14400000);                 // N*4      = 200,000
    int*    cnt_c = (int*)   (ws + 14600000);                 // N*4      = 200,000
    int*    off_r = (int*)   (ws + 14800000);                 // (N+1)*4 -> pad 200,016
    int*    off_c = (int*)   (ws + 15000016);                 // pad 200,016
    int*    eid_r = (int*)   (ws + 15200032);                 // E*4      = 3,200,000
    int*    eid_c = (int*)   (ws + 18400032);                 // E*4      = 3,200,000

    // zero both degree arrays in one shot (they are adjacent)
    hipMemsetAsync(cnt_r, 0, 400000, stream);

    const int block = 256;
    const int gridE = (N_EDGES + block - 1) / block;

    k_hist<<<gridE, block, 0, stream>>>(ei, cnt_r, cnt_c);
    k_scan2<<<1, SCAN_T, 0, stream>>>(cnt_r, off_r, cnt_c, off_c);
    k_logits_fill<<<gridE, block, 0, stream>>>(k0, k1, q0, q1, ei, e_buf,
                                               cnt_r, cnt_c, eid_r, eid_c);
    k_s<<<(N_NODES * 8 + block - 1) / block, block, 0, stream>>>(e_buf, off_r, eid_r, s);
    k_out<<<(N_NODES * 64 + block - 1) / block, block, 0, stream>>>(
        v0, v1, ei, e_buf, s, off_c, eid_c, out0, out1);
}